// Round 10
// baseline (41.343 us; speedup 1.0000x reference)
//
#include <hip/hip_runtime.h>

#define IN_F  1024
#define HID_F 1024
#define OUT_F 512
#define BATCH 128

__device__ __forceinline__ float sigm(float v) { return 1.0f / (1.0f + __expf(-v)); }

typedef __attribute__((ext_vector_type(8))) float f32x8;
typedef __attribute__((ext_vector_type(4))) float f32x4;

// Scalar-pipe broadcast loads at wave-uniform addresses -> SGPRs.
// SMEM completes out of order: only lgkmcnt(0) is a safe wait, so waits are
// batched 4-deep. Tied "+s" operands order consumers after the wait.
__device__ __forceinline__ f32x8 sld8(const float* p, int off_bytes) {
    f32x8 r;
    asm volatile("s_load_dwordx8 %0, %1, %2" : "=&s"(r) : "s"(p), "s"(off_bytes));
    return r;
}
__device__ __forceinline__ f32x4 sld4(const float* p, int off_bytes) {
    f32x4 r;
    asm volatile("s_load_dwordx4 %0, %1, %2" : "=&s"(r) : "s"(p), "s"(off_bytes));
    return r;
}
__device__ __forceinline__ void swait8x4(f32x8& a, f32x8& b, f32x8& c, f32x8& d) {
    asm volatile("s_waitcnt lgkmcnt(0)" : "+s"(a), "+s"(b), "+s"(c), "+s"(d));
}
__device__ __forceinline__ void swait4x4(f32x4& a, f32x4& b, f32x4& c, f32x4& d) {
    asm volatile("s_waitcnt lgkmcnt(0)" : "+s"(a), "+s"(b), "+s"(c), "+s"(d));
}
__device__ __forceinline__ void swait1(f32x8& a) {
    asm volatile("s_waitcnt lgkmcnt(0)" : "+s"(a));
}

// kPre: S1 [0,256): per (i,j): w=sigm(w1), s=sigm(s1), A=1-ws, C=w(2s-1);
//                   Dm[i][j]=C/A (A in (0.61,0.86): safe);
//                   PA16[i/16][j] = prod of A over 16-i subchunk.
//       S2 [256,768): w2s = sigm(w2)   (layout [j][o], o-contig, same as w2)
//       S3 [768,896): transpose x -> xt[1024][128]
__global__ __launch_bounds__(256) void kPre(const float* __restrict__ x,
                                            const float* __restrict__ w1,
                                            const float* __restrict__ s1,
                                            const float* __restrict__ w2,
                                            float* __restrict__ xt,
                                            float* __restrict__ Dm,
                                            float* __restrict__ PA16,
                                            float* __restrict__ w2s) {
    const int bx = blockIdx.x, tid = threadIdx.x;
    if (bx < 256) {
        const int sc = bx >> 2;                 // 0..63 (16-i subchunk)
        const int j  = (bx & 3) * 256 + tid;    // 0..1023
        float pa = 1.0f;
#pragma unroll 4
        for (int ii = 0; ii < 16; ++ii) {
            const int i = sc * 16 + ii;
            const float w = sigm(w1[(size_t)i * HID_F + j]);
            const float s = sigm(s1[(size_t)i * HID_F + j]);
            const float A = 1.0f - w * s;
            const float C = w * (2.0f * s - 1.0f);
            Dm[(size_t)i * HID_F + j] = C / A;
            pa *= A;
        }
        PA16[(size_t)sc * HID_F + j] = pa;
    } else if (bx < 768) {
        const int e = ((bx - 256) * 256 + tid) * 4;
        const float4 v = *(const float4*)(w2 + e);
        float4 r;
        r.x = sigm(v.x); r.y = sigm(v.y); r.z = sigm(v.z); r.w = sigm(v.w);
        *(float4*)(w2s + e) = r;
    } else {
        __shared__ float tile[32][33];
        const int bt = bx - 768;
        const int i0 = (bt & 31) * 32, b0 = (bt >> 5) * 32;
        const int tx = tid & 31, ty = tid >> 5;
#pragma unroll
        for (int r = 0; r < 32; r += 8)
            tile[ty + r][tx] = x[(size_t)(b0 + ty + r) * IN_F + i0 + tx];
        __syncthreads();
#pragma unroll
        for (int r = 0; r < 32; r += 8)
            xt[(size_t)(i0 + ty + r) * BATCH + b0 + tx] = tile[tx][ty + r];
    }
}

// k1h: full layer 1, ht written directly (no P intermediate).
// grid (128 j-tiles of 8, 2 b-halves) = 256 blocks x 1024 thr (16 waves).
// lanes = b (coalesced x loads); wave w covers i in [w*64,(w+1)*64);
// D/PA arrive via s_load (SGPR broadcast); LDS combine of 16 wave-partials.
__global__ __launch_bounds__(1024, 4) void k1h(const float* __restrict__ Dm,
                                               const float* __restrict__ PA16,
                                               const float* __restrict__ xt,
                                               float* __restrict__ ht) {
    __shared__ float ps[16][8][64];    // 32 KB
    const int tid  = threadIdx.x;
    const int lane = tid & 63;
    const int wvu  = __builtin_amdgcn_readfirstlane(tid >> 6);  // 0..15
    const int j0   = blockIdx.x * 8;
    const int bh   = blockIdx.y;
    const int b    = bh * 64 + lane;
    const int i0   = wvu * 64;

    float acc[8];
#pragma unroll
    for (int k = 0; k < 8; ++k) acc[k] = 1.0f;

    const float* xp = xt + (size_t)i0 * BATCH + b;      // per-lane, coalesced
    const int dbase = (i0 * HID_F + j0) * 4;            // uniform byte offset

#pragma unroll 1
    for (int sc = 0; sc < 4; ++sc) {                    // 4 subchunks x 16 i
        f32x8 pa = sld8(PA16, ((wvu * 4 + sc) * HID_F + j0) * 4);
#pragma unroll 1
        for (int bt = 0; bt < 4; ++bt) {                // 4 i per batch
            const int ib = sc * 16 + bt * 4;
            f32x8 d0 = sld8(Dm, dbase + (ib + 0) * (HID_F * 4));
            f32x8 d1 = sld8(Dm, dbase + (ib + 1) * (HID_F * 4));
            f32x8 d2 = sld8(Dm, dbase + (ib + 2) * (HID_F * 4));
            f32x8 d3 = sld8(Dm, dbase + (ib + 3) * (HID_F * 4));
            const float x0 = xp[(ib + 0) * BATCH];
            const float x1 = xp[(ib + 1) * BATCH];
            const float x2 = xp[(ib + 2) * BATCH];
            const float x3 = xp[(ib + 3) * BATCH];
            swait8x4(d0, d1, d2, d3);
#pragma unroll
            for (int jj = 0; jj < 8; ++jj) {
                acc[jj] *= fmaf(x0, d0[jj], 1.0f);
                acc[jj] *= fmaf(x1, d1[jj], 1.0f);
                acc[jj] *= fmaf(x2, d2[jj], 1.0f);
                acc[jj] *= fmaf(x3, d3[jj], 1.0f);
            }
        }
        swait1(pa);
#pragma unroll
        for (int jj = 0; jj < 8; ++jj) acc[jj] *= pa[jj];
    }

#pragma unroll
    for (int jj = 0; jj < 8; ++jj) ps[wvu][jj][lane] = acc[jj];
    __syncthreads();
    if (tid < 512) {
        const int j = tid >> 6, bb = tid & 63;
        float p = 1.0f;
#pragma unroll
        for (int w = 0; w < 16; ++w) p *= ps[w][j][bb];
        ht[(size_t)(j0 + j) * BATCH + bh * 64 + bb] = p;   // coalesced 256B runs
    }
}

// k2o: full layer 2, out written directly (no Q intermediate).
// grid (128 o-tiles of 4, 2 b-halves) = 256 blocks x 1024 thr (16 waves).
// lanes = b (coalesced ht loads); wave w covers j in [w*64,(w+1)*64);
// w2s via s_load broadcast; LDS combine of 16 wave-partials.
__global__ __launch_bounds__(1024, 4) void k2o(const float* __restrict__ w2s,
                                               const float* __restrict__ ht,
                                               float* __restrict__ out) {
    __shared__ float ps2[16][4][64];   // 16 KB
    const int tid  = threadIdx.x;
    const int lane = tid & 63;
    const int wvu  = __builtin_amdgcn_readfirstlane(tid >> 6);  // 0..15
    const int o0   = blockIdx.x * 4;
    const int bh   = blockIdx.y;
    const int b    = bh * 64 + lane;
    const int j0w  = wvu * 64;

    float acc[4] = {1.0f, 1.0f, 1.0f, 1.0f};
    const float* hp = ht + (size_t)j0w * BATCH + b;
    const int wbase = (j0w * OUT_F + o0) * 4;

#pragma unroll 1
    for (int bt = 0; bt < 16; ++bt) {                   // 4 j per batch
        const int jb = bt * 4;
        f32x4 w0 = sld4(w2s, wbase + (jb + 0) * (OUT_F * 4));
        f32x4 w1 = sld4(w2s, wbase + (jb + 1) * (OUT_F * 4));
        f32x4 w2_ = sld4(w2s, wbase + (jb + 2) * (OUT_F * 4));
        f32x4 w3 = sld4(w2s, wbase + (jb + 3) * (OUT_F * 4));
        const float h0 = hp[(jb + 0) * BATCH];
        const float h1 = hp[(jb + 1) * BATCH];
        const float h2 = hp[(jb + 2) * BATCH];
        const float h3 = hp[(jb + 3) * BATCH];
        swait4x4(w0, w1, w2_, w3);
#pragma unroll
        for (int oo = 0; oo < 4; ++oo) {
            acc[oo] *= fmaf(-h0, w0[oo], 1.0f);
            acc[oo] *= fmaf(-h1, w1[oo], 1.0f);
            acc[oo] *= fmaf(-h2, w2_[oo], 1.0f);
            acc[oo] *= fmaf(-h3, w3[oo], 1.0f);
        }
    }

#pragma unroll
    for (int oo = 0; oo < 4; ++oo) ps2[wvu][oo][lane] = acc[oo];
    __syncthreads();
    if (tid < 256) {
        const int o = tid >> 6, bb = tid & 63;
        float p = 1.0f;
#pragma unroll
        for (int w = 0; w < 16; ++w) p *= ps2[w][o][bb];
        out[(size_t)(bh * 64 + bb) * OUT_F + o0 + o] = 1.0f - p;
    }
}

extern "C" void kernel_launch(void* const* d_in, const int* in_sizes, int n_in,
                              void* d_out, int out_size, void* d_ws, size_t ws_size,
                              hipStream_t stream) {
    const float* x  = (const float*)d_in[0];
    const float* w1 = (const float*)d_in[1];
    const float* s1 = (const float*)d_in[2];
    const float* w2 = (const float*)d_in[3];
    float* out = (float*)d_out;

    // ws layout (floats): Dm 4MB | PA16 256KB | w2s 2MB | xt 512KB | ht 512KB
    float* Dm   = (float*)d_ws;
    float* PA16 = Dm + (size_t)IN_F * HID_F;
    float* w2s  = PA16 + (size_t)64 * HID_F;
    float* xt   = w2s + (size_t)HID_F * OUT_F;
    float* ht   = xt + (size_t)IN_F * BATCH;

    kPre<<<896, 256, 0, stream>>>(x, w1, s1, w2, xt, Dm, PA16, w2s);
    k1h<<<dim3(HID_F / 8, 2), 1024, 0, stream>>>(Dm, PA16, xt, ht);
    k2o<<<dim3(OUT_F / 4, 2), 1024, 0, stream>>>(w2s, ht, out);
}